// Round 3
// baseline (1169.636 us; speedup 1.0000x reference)
//
#include <hip/hip_runtime.h>
#include <stdint.h>

#define D 1024
#define N 200000
#define C 50
#define B 4096
#define CLS 4

// ws float offsets
static const size_t OFF_DOTS = 0;                        // C*N floats
static const size_t OFF_U    = (size_t)C * N;            // C*N uints
static const size_t OFF_GRAM = 2 * (size_t)C * N;        // C*C
static const size_t OFF_CSQ  = OFF_GRAM + C * C;         // C
static const size_t OFF_WC   = OFF_CSQ + C;              // CLS*C
static const size_t OFF_SUMS = OFF_WC + CLS * C;         // C
static const size_t OFF_W8   = OFF_SUMS + C;             // D*8 (16B aligned)

__device__ __forceinline__ unsigned mapf(float v) {
    unsigned u = __float_as_uint(v);
    return (u & 0x80000000u) ? ~u : (u | 0x80000000u);
}

__device__ __forceinline__ float dist2_of(float csq, float tesq, float dot) {
    return fmaf(-2.0f, dot, csq + tesq);
}

__device__ __forceinline__ float blk_reduce_1024(float v, float* red, int t) {
    #pragma unroll
    for (int off = 32; off > 0; off >>= 1) v += __shfl_down(v, off, 64);
    __syncthreads();
    if ((t & 63) == 0) red[t >> 6] = v;
    __syncthreads();
    if (t == 0) { float s = 0.f; for (int w = 0; w < 16; ++w) s += red[w]; red[0] = s; }
    __syncthreads();
    return red[0];
}

// ---------------- K1a: gram, scalar metrics, csq, wc -----------------
__global__ __launch_bounds__(1024) void k1a_gram(
    const float* __restrict__ concept, const float* __restrict__ hxw,
    float* __restrict__ ws, float* __restrict__ out)
{
    __shared__ __align__(16) float ct[64 * 50];
    __shared__ float gram[C * C];
    __shared__ float red[16];

    int t = threadIdx.x;

    float g[3] = {0.f, 0.f, 0.f};
    for (int d0 = 0; d0 < D; d0 += 64) {
        __syncthreads();
        for (int i = t; i < 64 * 50; i += 1024) ct[i] = concept[d0 * 50 + i];
        __syncthreads();
        #pragma unroll
        for (int s = 0; s < 3; ++s) {
            int p = t + s * 1024;
            if (p < C * C) {
                int i = p / C, j = p % C;
                float acc = g[s];
                for (int dd = 0; dd < 64; ++dd)
                    acc = fmaf(ct[dd * 50 + i], ct[dd * 50 + j], acc);
                g[s] = acc;
            }
        }
    }
    __syncthreads();
    #pragma unroll
    for (int s = 0; s < 3; ++s) {
        int p = t + s * 1024;
        if (p < C * C) gram[p] = g[s];
    }
    __syncthreads();

    for (int p = t; p < C * C; p += 1024) ws[OFF_GRAM + p] = gram[p];
    if (t < C) ws[OFF_CSQ + t] = gram[t * C + t];

    float s_all = 0.f, s_tr = 0.f, s_abs = 0.f;
    for (int p = t; p < C * C; p += 1024) {
        float v = gram[p];
        int i = p / C, j = p % C;
        float e = (i == j) ? 1.0f : 0.0f;
        s_all += v;
        if (i == j) s_tr += v;
        s_abs += fabsf(v - e);
    }
    float tot_all = blk_reduce_1024(s_all, red, t);
    float tot_tr  = blk_reduce_1024(s_tr,  red, t);
    float tot_abs = blk_reduce_1024(s_abs, red, t);
    if (t == 0) {
        out[32769] = (tot_all - tot_tr) / 2500.0f;  // L_sparse_2
        out[32770] = tot_tr / 2500.0f;              // norm_metrics
        out[32771] = tot_abs / 2500.0f;             // similarity_penalty
    }

    // wc[j][c] = sum_d hxw[j,d] * concept[d,c]
    if (t < CLS * C) {
        int j = t / C, c = t % C;
        float acc = 0.f;
        for (int d = 0; d < D; ++d)
            acc = fmaf(hxw[j * D + d], concept[d * C + c], acc);
        ws[OFF_WC + j * C + c] = acc;
    }
}

// ---------------- K1b: invert gram (single wave) + W8 = [hxw^T | Wy] -----------------
__global__ __launch_bounds__(64) void k1b_inv_w8(
    const float* __restrict__ concept, const float* __restrict__ hxw,
    float* __restrict__ ws)
{
    __shared__ float M[C * 100];   // [gram | I]
    __shared__ float colp[C];
    __shared__ float T[C * 4];
    int t = threadIdx.x;

    for (int p = t; p < C * 100; p += 64) {
        int r = p / 100, j = p % 100;
        M[p] = (j < C) ? ws[OFF_GRAM + r * C + j] : ((j - C) == r ? 1.0f : 0.0f);
    }
    __syncthreads();

    // pivotless Gauss-Jordan (gram is strictly diagonally dominant: diag~1024, off-diag ~<100)
    for (int pc = 0; pc < C; ++pc) {
        if (t < C) colp[t] = M[t * 100 + pc];
        __syncthreads();
        float pinv = 1.0f / colp[pc];
        for (int j = t; j < 100; j += 64) M[pc * 100 + j] *= pinv;
        __syncthreads();
        float mp0 = M[pc * 100 + t];
        float mp1 = (t + 64 < 100) ? M[pc * 100 + t + 64] : 0.f;
        for (int r = 0; r < C; ++r) {
            if (r == pc) continue;
            float f = colp[r];
            M[r * 100 + t] = fmaf(-f, mp0, M[r * 100 + t]);
            if (t + 64 < 100)
                M[r * 100 + t + 64] = fmaf(-f, mp1, M[r * 100 + t + 64]);
        }
        __syncthreads();
    }

    // T[c][j] = sum_cc inv[c][cc] * wc[j][cc]
    for (int p = t; p < C * 4; p += 64) {
        int c = p >> 2, j = p & 3;
        float acc = 0.f;
        for (int cc = 0; cc < C; ++cc)
            acc = fmaf(M[c * 100 + 50 + cc], ws[OFF_WC + j * C + cc], acc);
        T[p] = acc;
    }
    __syncthreads();

    // w8[d*8 + j]: j<4 -> hxw[j][d], j>=4 -> Wy[d][j-4] = sum_c concept[d][c]*T[c][j-4]
    for (int d = t; d < D; d += 64) {
        float4 lo, hi;
        lo.x = hxw[0 * D + d]; lo.y = hxw[1 * D + d];
        lo.z = hxw[2 * D + d]; lo.w = hxw[3 * D + d];
        float wy0 = 0.f, wy1 = 0.f, wy2 = 0.f, wy3 = 0.f;
        for (int c = 0; c < C; ++c) {
            float cv = concept[d * 50 + c];
            wy0 = fmaf(cv, T[c * 4 + 0], wy0);
            wy1 = fmaf(cv, T[c * 4 + 1], wy1);
            wy2 = fmaf(cv, T[c * 4 + 2], wy2);
            wy3 = fmaf(cv, T[c * 4 + 3], wy3);
        }
        hi.x = wy0; hi.y = wy1; hi.z = wy2; hi.w = wy3;
        *(float4*)(ws + OFF_W8 + (size_t)d * 8)     = lo;
        *(float4*)(ws + OFF_W8 + (size_t)d * 8 + 4) = hi;
    }
}

// ---------------- Kpred: [orig_pred | y_pred] = X @ W8 + bias -----------------
__global__ __launch_bounds__(256) void kpred(
    const float* __restrict__ X, const float* __restrict__ hxb,
    const float* __restrict__ ws, float* __restrict__ out)
{
    int t = threadIdx.x;
    int lane = t & 63, w = t >> 6;
    int r = blockIdx.x * 4 + w;
    const float* xr = X + (size_t)r * D;
    const float* w8 = ws + OFF_W8;

    float acc[8];
    #pragma unroll
    for (int j = 0; j < 8; ++j) acc[j] = 0.f;
    #pragma unroll
    for (int i = 0; i < 16; ++i) {
        int d = i * 64 + lane;
        float x = xr[d];
        float4 lo = *(const float4*)(w8 + (size_t)d * 8);
        float4 hi = *(const float4*)(w8 + (size_t)d * 8 + 4);
        acc[0] = fmaf(x, lo.x, acc[0]);
        acc[1] = fmaf(x, lo.y, acc[1]);
        acc[2] = fmaf(x, lo.z, acc[2]);
        acc[3] = fmaf(x, lo.w, acc[3]);
        acc[4] = fmaf(x, hi.x, acc[4]);
        acc[5] = fmaf(x, hi.y, acc[5]);
        acc[6] = fmaf(x, hi.z, acc[6]);
        acc[7] = fmaf(x, hi.w, acc[7]);
    }
    #pragma unroll
    for (int j = 0; j < 8; ++j) {
        float v = acc[j];
        #pragma unroll
        for (int off = 32; off > 0; off >>= 1) v += __shfl_down(v, off, 64);
        if (lane == 0) {
            float b = hxb[j & 3];
            if (j < 4) out[(size_t)r * CLS + j] = v + b;
            else       out[16384 + (size_t)r * CLS + (j - 4)] = v + b;
        }
    }
}

// ---------------- K3: dots + u = mapf(dist2) -----------------
__global__ __launch_bounds__(256) void k3_dots(
    const float* __restrict__ concept, const float* __restrict__ te,
    const float* __restrict__ csqp, float* __restrict__ dots_out,
    unsigned* __restrict__ u_out)
{
    int n = blockIdx.x * 256 + threadIdx.x;
    if (n >= N) return;   // no barriers in this kernel

    float acc[50];
    #pragma unroll
    for (int c = 0; c < 50; ++c) acc[c] = 0.f;
    float tesq = 0.f;

    const float* tp = te + n;
    for (int d0 = 0; d0 < D; d0 += 8) {
        float x[8];
        #pragma unroll
        for (int u = 0; u < 8; ++u)
            x[u] = tp[(size_t)(d0 + u) * N];
        #pragma unroll
        for (int u = 0; u < 8; ++u) {
            tesq = fmaf(x[u], x[u], tesq);
            const float* crow = concept + (d0 + u) * 50;  // wave-uniform -> scalar loads
            #pragma unroll
            for (int c = 0; c < 50; ++c)
                acc[c] = fmaf(x[u], crow[c], acc[c]);
        }
    }

    #pragma unroll
    for (int c = 0; c < 50; ++c) {
        dots_out[(size_t)c * N + n] = acc[c];
        u_out[(size_t)c * N + n] = mapf(dist2_of(csqp[c], tesq, acc[c]));
    }
}

// ---------------- K4: exact top-k (3-pass radix on u) + dot-sum, one block per concept -----------------
__global__ __launch_bounds__(1024) void k4_select(
    const float* __restrict__ ws, float* __restrict__ wsw,
    const int* __restrict__ topk)
{
    int c = blockIdx.x, t = threadIdx.x;
    const unsigned* uarr = (const unsigned*)(ws + OFF_U) + (size_t)c * N;
    const float* dots = ws + (size_t)c * N;

    __shared__ unsigned hist[4096];
    __shared__ unsigned wsum[16], woff[16];
    __shared__ unsigned sh_prefix;
    __shared__ int sh_rem;
    __shared__ int tieidx[128];
    __shared__ int tiecnt;
    __shared__ float fred[16];

    unsigned prefix = 0;
    int rem = *topk;
    int lane = t & 63, wid = t >> 6;

    #pragma unroll 1
    for (int pass = 0; pass < 3; ++pass) {
        int shift = (pass == 0) ? 20 : (pass == 1) ? 8 : 0;
        int bins  = (pass == 2) ? 256 : 4096;
        unsigned himask = (pass == 0) ? 0u : (pass == 1) ? 0xFFF00000u : 0xFFFFFF00u;

        for (int i = t; i < 4096; i += 1024) hist[i] = 0u;
        __syncthreads();
        for (int n = t; n < N; n += 1024) {
            unsigned u = uarr[n];
            if ((u & himask) == prefix)
                atomicAdd(&hist[(u >> shift) & (bins - 1)], 1u);
        }
        __syncthreads();

        // parallel cutoff pick: prefix-scan of 4-bin partial sums
        unsigned b0 = (unsigned)t * 4u;
        unsigned h0 = 0, h1 = 0, h2 = 0, h3 = 0, s4 = 0;
        if (b0 < (unsigned)bins) {
            h0 = hist[b0]; h1 = hist[b0 + 1]; h2 = hist[b0 + 2]; h3 = hist[b0 + 3];
            s4 = h0 + h1 + h2 + h3;
        }
        unsigned x = s4;
        #pragma unroll
        for (int off = 1; off < 64; off <<= 1) {
            unsigned y = (unsigned)__shfl_up((int)x, off, 64);
            if (lane >= off) x += y;
        }
        if (lane == 63) wsum[wid] = x;
        __syncthreads();
        if (t == 0) {
            unsigned run = 0;
            for (int w = 0; w < 16; ++w) { woff[w] = run; run += wsum[w]; }
        }
        __syncthreads();
        unsigned cumBefore = woff[wid] + x - s4;
        unsigned remu = (unsigned)rem;
        if (b0 < (unsigned)bins && cumBefore < remu && remu <= cumBefore + s4) {
            unsigned cum = cumBefore, bin = b0, r2 = 1;
            unsigned hh[4] = {h0, h1, h2, h3};
            #pragma unroll
            for (int j = 0; j < 4; ++j) {
                if (cum + hh[j] >= remu) { bin = b0 + j; r2 = remu - cum; break; }
                cum += hh[j];
            }
            sh_prefix = prefix | (bin << shift);
            sh_rem = (int)r2;
        }
        __syncthreads();
        prefix = sh_prefix;
        rem = sh_rem;
        __syncthreads();
    }

    // final: sum dots with u < prefix; collect exact-threshold ties
    if (t == 0) tiecnt = 0;
    __syncthreads();
    float lsum = 0.f;
    for (int n = t; n < N; n += 1024) {
        unsigned u = uarr[n];
        if (u < prefix) lsum += dots[n];
        else if (u == prefix) {
            int s = atomicAdd(&tiecnt, 1);
            if (s < 128) tieidx[s] = n;
        }
    }
    #pragma unroll
    for (int off = 32; off > 0; off >>= 1) lsum += __shfl_down(lsum, off, 64);
    __syncthreads();
    if (lane == 0) fred[wid] = lsum;
    __syncthreads();
    if (t == 0) {
        float tot = 0.f;
        for (int w = 0; w < 16; ++w) tot += fred[w];
        int cnt = tiecnt; if (cnt > 128) cnt = 128;
        int r = rem; if (r > cnt) r = cnt;
        // take ties by lowest index (matches lax.top_k stability)
        for (int s = 0; s < r; ++s) {
            int bi = -1, bv = 0x7FFFFFFF;
            for (int i = 0; i < cnt; ++i) {
                int vi = tieidx[i];
                if (vi >= 0 && vi < bv) { bv = vi; bi = i; }
            }
            if (bi >= 0) { tot += dots[bv]; tieidx[bi] = -1; }
        }
        wsw[OFF_SUMS + c] = tot;
    }
}

// ---------------- K5: L_sparse_1 -----------------
__global__ __launch_bounds__(64) void k5_final(const float* __restrict__ ws,
                                               float* __restrict__ out,
                                               const int* __restrict__ topk)
{
    int t = threadIdx.x;
    float v = (t < C) ? ws[OFF_SUMS + t] : 0.f;
    #pragma unroll
    for (int off = 32; off > 0; off >>= 1) v += __shfl_down(v, off, 64);
    if (t == 0) out[32768] = v / (float)((*topk) * C);
}

extern "C" void kernel_launch(void* const* d_in, const int* in_sizes, int n_in,
                              void* d_out, int out_size, void* d_ws, size_t ws_size,
                              hipStream_t stream) {
    (void)in_sizes; (void)n_in; (void)out_size; (void)ws_size;
    const float* concept = (const float*)d_in[0];
    const float* te      = (const float*)d_in[1];
    const float* X       = (const float*)d_in[2];
    const float* hxw     = (const float*)d_in[3];
    const float* hxb     = (const float*)d_in[4];
    const int*   topk    = (const int*)d_in[5];
    float* out = (float*)d_out;
    float* ws  = (float*)d_ws;

    k1a_gram<<<dim3(1), dim3(1024), 0, stream>>>(concept, hxw, ws, out);
    k1b_inv_w8<<<dim3(1), dim3(64), 0, stream>>>(concept, hxw, ws);
    k3_dots<<<dim3((N + 255) / 256), dim3(256), 0, stream>>>(
        concept, te, ws + OFF_CSQ, ws, (unsigned*)(ws + OFF_U));
    kpred<<<dim3(B / 4), dim3(256), 0, stream>>>(X, hxb, ws, out);
    k4_select<<<dim3(C), dim3(1024), 0, stream>>>(ws, ws, topk);
    k5_final<<<dim3(1), dim3(64), 0, stream>>>(ws, out, topk);
}

// Round 4
// 828.901 us; speedup vs baseline: 1.4111x; 1.4111x over previous
//
#include <hip/hip_runtime.h>
#include <stdint.h>

#define D 1024
#define N 200000
#define C 50
#define B 4096
#define CLS 4
#define KParts 16
#define CAP 4096

// ws float offsets
static const size_t OFF_DOTS  = 0;                          // C*N floats
static const size_t OFF_TESQ  = (size_t)C * N;              // N
static const size_t OFF_GPART = OFF_TESQ + N;               // KParts*2500
static const size_t OFF_WPART = OFF_GPART + KParts * 2500;  // KParts*200
static const size_t OFF_SUMS  = OFF_WPART + KParts * 200;   // C
static const size_t OFF_W8    = ((OFF_SUMS + C + 3) / 4) * 4; // D*8, float4-aligned

__device__ __forceinline__ unsigned mapf(float v) {
    unsigned u = __float_as_uint(v);
    return (u & 0x80000000u) ? ~u : (u | 0x80000000u);
}

// key for ordering: tesq - 2*dot (monotone with dist2; csq is per-concept constant)
__device__ __forceinline__ unsigned keyu(float dot, float tesq) {
    return mapf(fmaf(-2.0f, dot, tesq));
}

// ---------------- K1a: partial gram + partial wc, 16 blocks -----------------
__global__ __launch_bounds__(256) void k1a_partial(
    const float* __restrict__ concept, const float* __restrict__ hxw,
    float* __restrict__ ws)
{
    __shared__ __align__(16) float ct[64 * 50];
    __shared__ float hs[4 * 64];
    int t = threadIdx.x;
    int d0 = blockIdx.x * 64;

    for (int i = t; i < 64 * 50; i += 256) ct[i] = concept[d0 * 50 + i];
    {
        int j = t >> 6, dd = t & 63;
        hs[t] = hxw[j * D + d0 + dd];
    }
    __syncthreads();

    float* gp = ws + OFF_GPART + (size_t)blockIdx.x * 2500;
    for (int p = t; p < 2500; p += 256) {
        int i = p / 50, j = p - i * 50;
        float acc = 0.f;
        #pragma unroll 8
        for (int dd = 0; dd < 64; ++dd)
            acc = fmaf(ct[dd * 50 + i], ct[dd * 50 + j], acc);
        gp[p] = acc;
    }
    float* wp = ws + OFF_WPART + (size_t)blockIdx.x * 200;
    if (t < 200) {
        int j = t / 50, c = t - j * 50;
        float acc = 0.f;
        #pragma unroll 8
        for (int dd = 0; dd < 64; ++dd)
            acc = fmaf(hs[j * 64 + dd], ct[dd * 50 + c], acc);
        wp[t] = acc;
    }
}

// ---------------- K1b: sum partials, metrics, solve [G|wc^T], W8 -----------------
__global__ __launch_bounds__(256) void k1b_solve(
    const float* __restrict__ concept, const float* __restrict__ hxw,
    float* __restrict__ ws, float* __restrict__ out)
{
    __shared__ float gsh[2500];
    __shared__ float A[50 * 56];     // [G | wc^T | pad]
    __shared__ float colp[C];
    __shared__ float part[3][4];
    int t = threadIdx.x;
    int lane = t & 63, wid = t >> 6;

    // sum gram partials; metrics
    float s_all = 0.f, s_tr = 0.f, s_abs = 0.f;
    for (int p = t; p < 2500; p += 256) {
        float g = 0.f;
        #pragma unroll
        for (int b = 0; b < KParts; ++b)
            g += ws[OFF_GPART + (size_t)b * 2500 + p];
        gsh[p] = g;
        int i = p / 50, j = p - i * 50;
        float e = (i == j) ? 1.0f : 0.0f;
        s_all += g;
        if (i == j) s_tr += g;
        s_abs += fabsf(g - e);
    }
    #pragma unroll
    for (int off = 32; off > 0; off >>= 1) {
        s_all += __shfl_down(s_all, off, 64);
        s_tr  += __shfl_down(s_tr,  off, 64);
        s_abs += __shfl_down(s_abs, off, 64);
    }
    if (lane == 0) { part[0][wid] = s_all; part[1][wid] = s_tr; part[2][wid] = s_abs; }
    __syncthreads();
    if (t == 0) {
        float a = part[0][0] + part[0][1] + part[0][2] + part[0][3];
        float tr = part[1][0] + part[1][1] + part[1][2] + part[1][3];
        float ab = part[2][0] + part[2][1] + part[2][2] + part[2][3];
        out[32769] = (a - tr) / 2500.0f;   // L_sparse_2
        out[32770] = tr / 2500.0f;         // norm_metrics
        out[32771] = ab / 2500.0f;         // similarity_penalty
    }

    // build augmented [G | wc^T]
    for (int p = t; p < 50 * 56; p += 256) {
        int r = p / 56, col = p - r * 56;
        float v = 0.f;
        if (col < 50) v = gsh[r * 50 + col];
        else if (col < 54) {
            float w = 0.f;
            #pragma unroll
            for (int b = 0; b < KParts; ++b)
                w += ws[OFF_WPART + (size_t)b * 200 + (col - 50) * 50 + r];
            v = w;
        }
        A[p] = v;
    }
    __syncthreads();

    // pivotless Gauss-Jordan (G is SPD -> stable without pivoting)
    for (int pc = 0; pc < C; ++pc) {
        if (t < C) colp[t] = A[t * 56 + pc];
        __syncthreads();
        float pinv = 1.0f / colp[pc];
        if (t < 56) A[pc * 56 + t] *= pinv;
        __syncthreads();
        for (int p = t; p < 50 * 56; p += 256) {
            int r = p / 56, col = p - r * 56;
            if (r != pc) A[p] = fmaf(-colp[r], A[pc * 56 + col], A[p]);
        }
        __syncthreads();
    }

    // W8[d][0..3] = hxw[j][d]; W8[d][4..7] = sum_c concept[d][c]*T[c][j], T = A[:,50+j]
    for (int d = t; d < D; d += 256) {
        float wy0 = 0.f, wy1 = 0.f, wy2 = 0.f, wy3 = 0.f;
        for (int c = 0; c < C; ++c) {
            float cv = concept[d * 50 + c];
            wy0 = fmaf(cv, A[c * 56 + 50], wy0);
            wy1 = fmaf(cv, A[c * 56 + 51], wy1);
            wy2 = fmaf(cv, A[c * 56 + 52], wy2);
            wy3 = fmaf(cv, A[c * 56 + 53], wy3);
        }
        float4 lo, hi;
        lo.x = hxw[0 * D + d]; lo.y = hxw[1 * D + d];
        lo.z = hxw[2 * D + d]; lo.w = hxw[3 * D + d];
        hi.x = wy0; hi.y = wy1; hi.z = wy2; hi.w = wy3;
        *(float4*)(ws + OFF_W8 + (size_t)d * 8)     = lo;
        *(float4*)(ws + OFF_W8 + (size_t)d * 8 + 4) = hi;
    }
}

// ---------------- Kpred: [orig_pred | y_pred] = X @ W8 + bias -----------------
__global__ __launch_bounds__(256) void kpred(
    const float* __restrict__ X, const float* __restrict__ hxb,
    const float* __restrict__ ws, float* __restrict__ out)
{
    int t = threadIdx.x;
    int lane = t & 63, w = t >> 6;
    int r = blockIdx.x * 4 + w;
    const float* xr = X + (size_t)r * D;
    const float* w8 = ws + OFF_W8;

    float acc[8];
    #pragma unroll
    for (int j = 0; j < 8; ++j) acc[j] = 0.f;
    #pragma unroll
    for (int i = 0; i < 16; ++i) {
        int d = i * 64 + lane;
        float x = xr[d];
        float4 lo = *(const float4*)(w8 + (size_t)d * 8);
        float4 hi = *(const float4*)(w8 + (size_t)d * 8 + 4);
        acc[0] = fmaf(x, lo.x, acc[0]);
        acc[1] = fmaf(x, lo.y, acc[1]);
        acc[2] = fmaf(x, lo.z, acc[2]);
        acc[3] = fmaf(x, lo.w, acc[3]);
        acc[4] = fmaf(x, hi.x, acc[4]);
        acc[5] = fmaf(x, hi.y, acc[5]);
        acc[6] = fmaf(x, hi.z, acc[6]);
        acc[7] = fmaf(x, hi.w, acc[7]);
    }
    #pragma unroll
    for (int j = 0; j < 8; ++j) {
        float v = acc[j];
        #pragma unroll
        for (int off = 32; off > 0; off >>= 1) v += __shfl_down(v, off, 64);
        if (lane == 0) {
            float b = hxb[j & 3];
            if (j < 4) out[(size_t)r * CLS + j] = v + b;
            else       out[16384 + (size_t)r * CLS + (j - 4)] = v + b;
        }
    }
}

// ---------------- K3: dots + tesq, register-pipelined -----------------
__global__ __launch_bounds__(256) void k3_dots(
    const float* __restrict__ concept, const float* __restrict__ te,
    float* __restrict__ ws)
{
    int n = blockIdx.x * 256 + threadIdx.x;
    if (n >= N) return;   // N % 64 == 0 -> whole waves only, no barriers here

    float acc[50];
    #pragma unroll
    for (int c = 0; c < 50; ++c) acc[c] = 0.f;
    float tesq = 0.f;

    const float* tp = te + n;
    for (int d0 = 0; d0 < D; d0 += 8) {
        float x[8];
        #pragma unroll
        for (int u = 0; u < 8; ++u)
            x[u] = tp[(size_t)(d0 + u) * N];
        #pragma unroll
        for (int u = 0; u < 8; ++u) {
            tesq = fmaf(x[u], x[u], tesq);
            const float2* crow = (const float2*)(concept + (d0 + u) * 50); // wave-uniform
            #pragma unroll
            for (int q = 0; q < 25; ++q) {
                float2 cv = crow[q];
                acc[q * 2 + 0] = fmaf(x[u], cv.x, acc[q * 2 + 0]);
                acc[q * 2 + 1] = fmaf(x[u], cv.y, acc[q * 2 + 1]);
            }
        }
    }

    #pragma unroll
    for (int c = 0; c < 50; ++c) ws[(size_t)c * N + n] = acc[c];
    ws[OFF_TESQ + n] = tesq;
}

// ---------------- K4: exact top-k via range-binned select, one block/concept -----------------
__global__ __launch_bounds__(1024) void k4_select(
    const float* __restrict__ ws, float* __restrict__ wsw,
    const int* __restrict__ topk)
{
    int c = blockIdx.x, t = threadIdx.x;
    int lane = t & 63, wid = t >> 6;
    const float* dots = ws + (size_t)c * N;
    const float* tesq = ws + OFF_TESQ;

    __shared__ unsigned hist[4096];
    __shared__ unsigned wsum[16], woff[16];
    __shared__ unsigned wmin[16], wmax[16];
    __shared__ unsigned sh_ulo, sh_uhi;
    __shared__ unsigned sh_bin; __shared__ int sh_rem;
    __shared__ int cnt;
    __shared__ unsigned cand_u[CAP];
    __shared__ int      cand_i[CAP];
    __shared__ float    cand_d[CAP];
    __shared__ float fred[16];

    // ---- pass 0: per-concept u-range ----
    unsigned uminl = 0xFFFFFFFFu, umaxl = 0u;
    for (int n = t; n < N; n += 1024) {
        unsigned u = keyu(dots[n], tesq[n]);
        uminl = min(uminl, u); umaxl = max(umaxl, u);
    }
    #pragma unroll
    for (int off = 32; off > 0; off >>= 1) {
        uminl = min(uminl, (unsigned)__shfl_down((int)uminl, off, 64));
        umaxl = max(umaxl, (unsigned)__shfl_down((int)umaxl, off, 64));
    }
    if (lane == 0) { wmin[wid] = uminl; wmax[wid] = umaxl; }
    __syncthreads();
    if (t == 0) {
        unsigned mn = 0xFFFFFFFFu, mx = 0u;
        for (int w = 0; w < 16; ++w) { mn = min(mn, wmin[w]); mx = max(mx, wmax[w]); }
        sh_ulo = mn; sh_uhi = mx;
    }
    __syncthreads();
    unsigned ulo = sh_ulo, uhi = sh_uhi;
    int rem = *topk;

    // ---- 2 refinement iterations: linear bins over [ulo, uhi] ----
    #pragma unroll 1
    for (int iter = 0; iter < 2; ++iter) {
        unsigned long long width = (unsigned long long)(uhi - ulo) + 1ull;
        for (int i = t; i < 4096; i += 1024) hist[i] = 0u;
        __syncthreads();
        for (int n = t; n < N; n += 1024) {
            unsigned u = keyu(dots[n], tesq[n]);
            if (u >= ulo && u <= uhi) {
                unsigned bin = (unsigned)(((unsigned long long)(u - ulo) * 4096ull) / width);
                atomicAdd(&hist[bin], 1u);
            }
        }
        __syncthreads();
        // parallel cutoff pick
        unsigned b0 = (unsigned)t * 4u;
        unsigned h0 = hist[b0], h1 = hist[b0 + 1], h2 = hist[b0 + 2], h3 = hist[b0 + 3];
        unsigned s4 = h0 + h1 + h2 + h3;
        unsigned x = s4;
        #pragma unroll
        for (int off = 1; off < 64; off <<= 1) {
            unsigned y = (unsigned)__shfl_up((int)x, off, 64);
            if (lane >= off) x += y;
        }
        if (lane == 63) wsum[wid] = x;
        __syncthreads();
        if (t == 0) {
            unsigned run = 0;
            for (int w = 0; w < 16; ++w) { woff[w] = run; run += wsum[w]; }
        }
        __syncthreads();
        unsigned cumBefore = woff[wid] + x - s4;
        unsigned remu = (unsigned)rem;
        if (cumBefore < remu && remu <= cumBefore + s4) {
            unsigned cum = cumBefore, bin = b0, r2 = 1;
            unsigned hh[4] = {h0, h1, h2, h3};
            #pragma unroll
            for (int j = 0; j < 4; ++j) {
                if (cum + hh[j] >= remu) { bin = b0 + j; r2 = remu - cum; break; }
                cum += hh[j];
            }
            sh_bin = bin; sh_rem = (int)r2;
        }
        __syncthreads();
        unsigned b = sh_bin;
        rem = sh_rem;
        // narrow [ulo,uhi] to bin b's u-subrange
        unsigned nlo = ulo + (unsigned)(((unsigned long long)b * width + 4095ull) / 4096ull);
        unsigned nhi = ulo + (unsigned)((((unsigned long long)(b + 1) * width + 4095ull) / 4096ull) - 1ull);
        ulo = nlo; uhi = nhi;
        __syncthreads();
    }

    // ---- final: sum below range, collect candidates in range ----
    if (t == 0) cnt = 0;
    __syncthreads();
    float lsum = 0.f;
    for (int n = t; n < N; n += 1024) {
        float dv = dots[n];
        unsigned u = keyu(dv, tesq[n]);
        if (u < ulo) lsum += dv;
        else if (u <= uhi) {
            int s = atomicAdd(&cnt, 1);
            if (s < CAP) { cand_u[s] = u; cand_i[s] = n; cand_d[s] = dv; }
        }
    }
    __syncthreads();
    int cc = cnt < CAP ? cnt : CAP;
    // exact rank by (u, idx) among candidates; take rem smallest
    for (int ci = t; ci < cc; ci += 1024) {
        unsigned ui = cand_u[ci]; int ii = cand_i[ci];
        int rank = 0;
        for (int j = 0; j < cc; ++j) {
            unsigned uj = cand_u[j];
            rank += (uj < ui || (uj == ui && cand_i[j] < ii)) ? 1 : 0;
        }
        if (rank < rem) lsum += cand_d[ci];
    }
    #pragma unroll
    for (int off = 32; off > 0; off >>= 1) lsum += __shfl_down(lsum, off, 64);
    if (lane == 0) fred[wid] = lsum;
    __syncthreads();
    if (t == 0) {
        float tot = 0.f;
        for (int w = 0; w < 16; ++w) tot += fred[w];
        wsw[OFF_SUMS + c] = tot;
    }
}

// ---------------- K5: L_sparse_1 -----------------
__global__ __launch_bounds__(64) void k5_final(const float* __restrict__ ws,
                                               float* __restrict__ out,
                                               const int* __restrict__ topk)
{
    int t = threadIdx.x;
    float v = (t < C) ? ws[OFF_SUMS + t] : 0.f;
    #pragma unroll
    for (int off = 32; off > 0; off >>= 1) v += __shfl_down(v, off, 64);
    if (t == 0) out[32768] = v / (float)((*topk) * C);
}

extern "C" void kernel_launch(void* const* d_in, const int* in_sizes, int n_in,
                              void* d_out, int out_size, void* d_ws, size_t ws_size,
                              hipStream_t stream) {
    (void)in_sizes; (void)n_in; (void)out_size; (void)ws_size;
    const float* concept = (const float*)d_in[0];
    const float* te      = (const float*)d_in[1];
    const float* X       = (const float*)d_in[2];
    const float* hxw     = (const float*)d_in[3];
    const float* hxb     = (const float*)d_in[4];
    const int*   topk    = (const int*)d_in[5];
    float* out = (float*)d_out;
    float* ws  = (float*)d_ws;

    k3_dots<<<dim3((N + 255) / 256), dim3(256), 0, stream>>>(concept, te, ws);
    k1a_partial<<<dim3(KParts), dim3(256), 0, stream>>>(concept, hxw, ws);
    k1b_solve<<<dim3(1), dim3(256), 0, stream>>>(concept, hxw, ws, out);
    kpred<<<dim3(B / 4), dim3(256), 0, stream>>>(X, hxb, ws, out);
    k4_select<<<dim3(C), dim3(1024), 0, stream>>>(ws, ws, topk);
    k5_final<<<dim3(1), dim3(64), 0, stream>>>(ws, out, topk);
}

// Round 5
// 751.137 us; speedup vs baseline: 1.5572x; 1.1035x over previous
//
#include <hip/hip_runtime.h>
#include <stdint.h>

#define D 1024
#define N 200000
#define C 50
#define B 4096
#define CLS 4
#define KParts 16
#define CAP 4096
#define NB3 ((N + 255) / 256)   // 782 blocks for the dots part

typedef float v2f __attribute__((ext_vector_type(2)));

// ws float offsets
static const size_t OFF_DOTS  = 0;                          // C*N floats
static const size_t OFF_TESQ  = (size_t)C * N;              // N
static const size_t OFF_GPART = OFF_TESQ + N;               // KParts*2500
static const size_t OFF_WPART = OFF_GPART + KParts * 2500;  // KParts*200
static const size_t OFF_SUMS  = OFF_WPART + KParts * 200;   // C
static const size_t OFF_CNT   = OFF_SUMS + C;               // 1 (uint)
static const size_t OFF_W8    = ((OFF_CNT + 1 + 3) / 4) * 4; // D*8, float4-aligned

__device__ __forceinline__ unsigned mapf(float v) {
    unsigned u = __float_as_uint(v);
    return (u & 0x80000000u) ? ~u : (u | 0x80000000u);
}

// ordering key: tesq - 2*dot (monotone with dist2; csq is per-concept constant)
__device__ __forceinline__ unsigned keyu(float dot, float tesq) {
    return mapf(fmaf(-2.0f, dot, tesq));
}

// ---------------- KA: dots+tesq (782 blocks) fused with partial gram/wc (16 blocks) ----------
__global__ __launch_bounds__(256) void kA_dots_gram(
    const float* __restrict__ concept, const float* __restrict__ te,
    const float* __restrict__ hxw, float* __restrict__ ws)
{
    int t = threadIdx.x;
    if (blockIdx.x < NB3) {
        // ---- dots part: one column per thread, packed-f32 FMA ----
        int n = blockIdx.x * 256 + t;
        if (n >= N) return;   // whole-wave exits only in last block; no barriers here

        v2f acc[25];
        #pragma unroll
        for (int q = 0; q < 25; ++q) acc[q] = (v2f)(0.0f);
        float tesq = 0.f;

        const float* tp = te + n;
        for (int d0 = 0; d0 < D; d0 += 8) {
            float x[8];
            #pragma unroll
            for (int u = 0; u < 8; ++u)
                x[u] = tp[(size_t)(d0 + u) * N];
            #pragma unroll
            for (int u = 0; u < 8; ++u) {
                tesq = fmaf(x[u], x[u], tesq);
                const v2f* crow = (const v2f*)(concept + (d0 + u) * 50); // wave-uniform, 8B-aligned
                v2f xv; xv[0] = x[u]; xv[1] = x[u];
                #pragma unroll
                for (int q = 0; q < 25; ++q)
                    acc[q] = __builtin_elementwise_fma(xv, crow[q], acc[q]);
            }
        }

        #pragma unroll
        for (int q = 0; q < 25; ++q) {
            ws[(size_t)(2 * q) * N + n]     = acc[q][0];
            ws[(size_t)(2 * q + 1) * N + n] = acc[q][1];
        }
        ws[OFF_TESQ + n] = tesq;
    } else {
        // ---- partial gram + partial wc over a 64-row d-slab ----
        __shared__ __align__(16) float ct[64 * 50];
        __shared__ float hs[4 * 64];
        int bid = blockIdx.x - NB3;
        int d0 = bid * 64;

        for (int i = t; i < 64 * 50; i += 256) ct[i] = concept[d0 * 50 + i];
        {
            int j = t >> 6, dd = t & 63;
            hs[t] = hxw[j * D + d0 + dd];
        }
        __syncthreads();

        float* gp = ws + OFF_GPART + (size_t)bid * 2500;
        for (int p = t; p < 2500; p += 256) {
            int i = p / 50, j = p - i * 50;
            float acc = 0.f;
            #pragma unroll 8
            for (int dd = 0; dd < 64; ++dd)
                acc = fmaf(ct[dd * 50 + i], ct[dd * 50 + j], acc);
            gp[p] = acc;
        }
        float* wp = ws + OFF_WPART + (size_t)bid * 200;
        if (t < 200) {
            int j = t / 50, c = t - j * 50;
            float acc = 0.f;
            #pragma unroll 8
            for (int dd = 0; dd < 64; ++dd)
                acc = fmaf(hs[j * 64 + dd], ct[dd * 50 + c], acc);
            wp[t] = acc;
        }
    }
}

// ---------------- K1b: sum partials, metrics, solve [G|wc^T], W8, zero counter ----------
__global__ __launch_bounds__(256) void k1b_solve(
    const float* __restrict__ concept, const float* __restrict__ hxw,
    float* __restrict__ ws, float* __restrict__ out)
{
    __shared__ float gsh[2500];
    __shared__ float A[50 * 56];     // [G | wc^T | pad]
    __shared__ float colp[C];
    __shared__ float part[3][4];
    int t = threadIdx.x;
    int lane = t & 63, wid = t >> 6;

    if (t == 0) ((unsigned*)(ws + OFF_CNT))[0] = 0u;   // k4 completion counter

    float s_all = 0.f, s_tr = 0.f, s_abs = 0.f;
    for (int p = t; p < 2500; p += 256) {
        float g = 0.f;
        #pragma unroll
        for (int b = 0; b < KParts; ++b)
            g += ws[OFF_GPART + (size_t)b * 2500 + p];
        gsh[p] = g;
        int i = p / 50, j = p - i * 50;
        float e = (i == j) ? 1.0f : 0.0f;
        s_all += g;
        if (i == j) s_tr += g;
        s_abs += fabsf(g - e);
    }
    #pragma unroll
    for (int off = 32; off > 0; off >>= 1) {
        s_all += __shfl_down(s_all, off, 64);
        s_tr  += __shfl_down(s_tr,  off, 64);
        s_abs += __shfl_down(s_abs, off, 64);
    }
    if (lane == 0) { part[0][wid] = s_all; part[1][wid] = s_tr; part[2][wid] = s_abs; }
    __syncthreads();
    if (t == 0) {
        float a  = part[0][0] + part[0][1] + part[0][2] + part[0][3];
        float tr = part[1][0] + part[1][1] + part[1][2] + part[1][3];
        float ab = part[2][0] + part[2][1] + part[2][2] + part[2][3];
        out[32769] = (a - tr) / 2500.0f;   // L_sparse_2
        out[32770] = tr / 2500.0f;         // norm_metrics
        out[32771] = ab / 2500.0f;         // similarity_penalty
    }

    for (int p = t; p < 50 * 56; p += 256) {
        int r = p / 56, col = p - r * 56;
        float v = 0.f;
        if (col < 50) v = gsh[r * 50 + col];
        else if (col < 54) {
            float w = 0.f;
            #pragma unroll
            for (int b = 0; b < KParts; ++b)
                w += ws[OFF_WPART + (size_t)b * 200 + (col - 50) * 50 + r];
            v = w;
        }
        A[p] = v;
    }
    __syncthreads();

    // pivotless Gauss-Jordan (G is SPD -> stable without pivoting)
    for (int pc = 0; pc < C; ++pc) {
        if (t < C) colp[t] = A[t * 56 + pc];
        __syncthreads();
        float pinv = 1.0f / colp[pc];
        if (t < 56) A[pc * 56 + t] *= pinv;
        __syncthreads();
        for (int p = t; p < 50 * 56; p += 256) {
            int r = p / 56, col = p - r * 56;
            if (r != pc) A[p] = fmaf(-colp[r], A[pc * 56 + col], A[p]);
        }
        __syncthreads();
    }

    // W8[d][0..3] = hxw[j][d]; W8[d][4..7] = sum_c concept[d][c] * A[c][50+j]
    for (int d = t; d < D; d += 256) {
        float wy0 = 0.f, wy1 = 0.f, wy2 = 0.f, wy3 = 0.f;
        for (int c = 0; c < C; ++c) {
            float cv = concept[d * 50 + c];
            wy0 = fmaf(cv, A[c * 56 + 50], wy0);
            wy1 = fmaf(cv, A[c * 56 + 51], wy1);
            wy2 = fmaf(cv, A[c * 56 + 52], wy2);
            wy3 = fmaf(cv, A[c * 56 + 53], wy3);
        }
        float4 lo, hi;
        lo.x = hxw[0 * D + d]; lo.y = hxw[1 * D + d];
        lo.z = hxw[2 * D + d]; lo.w = hxw[3 * D + d];
        hi.x = wy0; hi.y = wy1; hi.z = wy2; hi.w = wy3;
        *(float4*)(ws + OFF_W8 + (size_t)d * 8)     = lo;
        *(float4*)(ws + OFF_W8 + (size_t)d * 8 + 4) = hi;
    }
}

// ---------------- Kpred: [orig_pred | y_pred] = X @ W8 + bias -----------------
__global__ __launch_bounds__(256) void kpred(
    const float* __restrict__ X, const float* __restrict__ hxb,
    const float* __restrict__ ws, float* __restrict__ out)
{
    int t = threadIdx.x;
    int lane = t & 63, w = t >> 6;
    int r = blockIdx.x * 4 + w;
    const float* xr = X + (size_t)r * D;
    const float* w8 = ws + OFF_W8;

    float acc[8];
    #pragma unroll
    for (int j = 0; j < 8; ++j) acc[j] = 0.f;
    #pragma unroll
    for (int i = 0; i < 16; ++i) {
        int d = i * 64 + lane;
        float x = xr[d];
        float4 lo = *(const float4*)(w8 + (size_t)d * 8);
        float4 hi = *(const float4*)(w8 + (size_t)d * 8 + 4);
        acc[0] = fmaf(x, lo.x, acc[0]);
        acc[1] = fmaf(x, lo.y, acc[1]);
        acc[2] = fmaf(x, lo.z, acc[2]);
        acc[3] = fmaf(x, lo.w, acc[3]);
        acc[4] = fmaf(x, hi.x, acc[4]);
        acc[5] = fmaf(x, hi.y, acc[5]);
        acc[6] = fmaf(x, hi.z, acc[6]);
        acc[7] = fmaf(x, hi.w, acc[7]);
    }
    #pragma unroll
    for (int j = 0; j < 8; ++j) {
        float v = acc[j];
        #pragma unroll
        for (int off = 32; off > 0; off >>= 1) v += __shfl_down(v, off, 64);
        if (lane == 0) {
            float b = hxb[j & 3];
            if (j < 4) out[(size_t)r * CLS + j] = v + b;
            else       out[16384 + (size_t)r * CLS + (j - 4)] = v + b;
        }
    }
}

// ---------------- K4: exact top-k (range + 1 refinement + final) + fused L_sparse_1 ----------
__global__ __launch_bounds__(1024) void k4_select(
    const float* __restrict__ ws, float* __restrict__ wsw,
    float* __restrict__ out, const int* __restrict__ topk)
{
    int c = blockIdx.x, t = threadIdx.x;
    int lane = t & 63, wid = t >> 6;
    const float* dots = ws + (size_t)c * N;
    const float* tesq = ws + OFF_TESQ;

    __shared__ unsigned hist[4096];
    __shared__ unsigned wsum[16], woff[16];
    __shared__ unsigned wmin[16], wmax[16];
    __shared__ unsigned sh_ulo, sh_uhi;
    __shared__ unsigned sh_bin; __shared__ int sh_rem;
    __shared__ int cnt;
    __shared__ unsigned cand_u[CAP];
    __shared__ int      cand_i[CAP];
    __shared__ float    cand_d[CAP];
    __shared__ float fred[16];

    // ---- pass 0: per-concept key range ----
    unsigned uminl = 0xFFFFFFFFu, umaxl = 0u;
    for (int n = t; n < N; n += 1024) {
        unsigned u = keyu(dots[n], tesq[n]);
        uminl = min(uminl, u); umaxl = max(umaxl, u);
    }
    #pragma unroll
    for (int off = 32; off > 0; off >>= 1) {
        uminl = min(uminl, (unsigned)__shfl_down((int)uminl, off, 64));
        umaxl = max(umaxl, (unsigned)__shfl_down((int)umaxl, off, 64));
    }
    if (lane == 0) { wmin[wid] = uminl; wmax[wid] = umaxl; }
    __syncthreads();
    if (t == 0) {
        unsigned mn = 0xFFFFFFFFu, mx = 0u;
        for (int w = 0; w < 16; ++w) { mn = min(mn, wmin[w]); mx = max(mx, wmax[w]); }
        sh_ulo = mn; sh_uhi = mx;
    }
    __syncthreads();
    unsigned ulo = sh_ulo, uhi = sh_uhi;
    int rem = *topk;

    // ---- 1 refinement: 4096 linear bins over [ulo, uhi] ----
    {
        unsigned long long width = (unsigned long long)(uhi - ulo) + 1ull;
        for (int i = t; i < 4096; i += 1024) hist[i] = 0u;
        __syncthreads();
        for (int n = t; n < N; n += 1024) {
            unsigned u = keyu(dots[n], tesq[n]);
            if (u >= ulo && u <= uhi) {
                unsigned bin = (unsigned)(((unsigned long long)(u - ulo) * 4096ull) / width);
                atomicAdd(&hist[bin], 1u);
            }
        }
        __syncthreads();
        unsigned b0 = (unsigned)t * 4u;
        unsigned h0 = hist[b0], h1 = hist[b0 + 1], h2 = hist[b0 + 2], h3 = hist[b0 + 3];
        unsigned s4 = h0 + h1 + h2 + h3;
        unsigned x = s4;
        #pragma unroll
        for (int off = 1; off < 64; off <<= 1) {
            unsigned y = (unsigned)__shfl_up((int)x, off, 64);
            if (lane >= off) x += y;
        }
        if (lane == 63) wsum[wid] = x;
        __syncthreads();
        if (t == 0) {
            unsigned run = 0;
            for (int w = 0; w < 16; ++w) { woff[w] = run; run += wsum[w]; }
        }
        __syncthreads();
        unsigned cumBefore = woff[wid] + x - s4;
        unsigned remu = (unsigned)rem;
        if (cumBefore < remu && remu <= cumBefore + s4) {
            unsigned cum = cumBefore, bin = b0, r2 = 1;
            unsigned hh[4] = {h0, h1, h2, h3};
            #pragma unroll
            for (int j = 0; j < 4; ++j) {
                if (cum + hh[j] >= remu) { bin = b0 + j; r2 = remu - cum; break; }
                cum += hh[j];
            }
            sh_bin = bin; sh_rem = (int)r2;
        }
        __syncthreads();
        unsigned b = sh_bin;
        rem = sh_rem;
        unsigned nlo = ulo + (unsigned)(((unsigned long long)b * width + 4095ull) / 4096ull);
        unsigned nhi = ulo + (unsigned)((((unsigned long long)(b + 1) * width + 4095ull) / 4096ull) - 1ull);
        ulo = nlo; uhi = nhi;
        __syncthreads();
    }

    // ---- final: sum below range, candidates in range, exact (u,idx)-rank ----
    if (t == 0) cnt = 0;
    __syncthreads();
    float lsum = 0.f;
    for (int n = t; n < N; n += 1024) {
        float dv = dots[n];
        unsigned u = keyu(dv, tesq[n]);
        if (u < ulo) lsum += dv;
        else if (u <= uhi) {
            int s = atomicAdd(&cnt, 1);
            if (s < CAP) { cand_u[s] = u; cand_i[s] = n; cand_d[s] = dv; }
        }
    }
    __syncthreads();
    int cc = cnt < CAP ? cnt : CAP;
    for (int ci = t; ci < cc; ci += 1024) {
        unsigned ui = cand_u[ci]; int ii = cand_i[ci];
        int rank = 0;
        for (int j = 0; j < cc; ++j) {
            unsigned uj = cand_u[j];
            rank += (uj < ui || (uj == ui && cand_i[j] < ii)) ? 1 : 0;
        }
        if (rank < rem) lsum += cand_d[ci];
    }
    #pragma unroll
    for (int off = 32; off > 0; off >>= 1) lsum += __shfl_down(lsum, off, 64);
    if (lane == 0) fred[wid] = lsum;
    __syncthreads();
    if (t == 0) {
        float tot = 0.f;
        for (int w = 0; w < 16; ++w) tot += fred[w];
        wsw[OFF_SUMS + c] = tot;
        __threadfence();
        unsigned done = atomicAdd((unsigned*)(wsw + OFF_CNT), 1u);
        if (done == C - 1) {
            // last block: deterministic fixed-order reduction (atomic reads for coherence)
            float s = 0.f;
            for (int i = 0; i < C; ++i) s += atomicAdd(&wsw[OFF_SUMS + i], 0.0f);
            out[32768] = s / (float)((*topk) * C);
        }
    }
}

extern "C" void kernel_launch(void* const* d_in, const int* in_sizes, int n_in,
                              void* d_out, int out_size, void* d_ws, size_t ws_size,
                              hipStream_t stream) {
    (void)in_sizes; (void)n_in; (void)out_size; (void)ws_size;
    const float* concept = (const float*)d_in[0];
    const float* te      = (const float*)d_in[1];
    const float* X       = (const float*)d_in[2];
    const float* hxw     = (const float*)d_in[3];
    const float* hxb     = (const float*)d_in[4];
    const int*   topk    = (const int*)d_in[5];
    float* out = (float*)d_out;
    float* ws  = (float*)d_ws;

    kA_dots_gram<<<dim3(NB3 + KParts), dim3(256), 0, stream>>>(concept, te, hxw, ws);
    k1b_solve<<<dim3(1), dim3(256), 0, stream>>>(concept, hxw, ws, out);
    kpred<<<dim3(B / 4), dim3(256), 0, stream>>>(X, hxb, ws, out);
    k4_select<<<dim3(C), dim3(1024), 0, stream>>>(ws, ws, out, topk);
}

// Round 6
// 698.363 us; speedup vs baseline: 1.6748x; 1.0756x over previous
//
#include <hip/hip_runtime.h>
#include <stdint.h>

#define D 1024
#define N 200000
#define C 50
#define B 4096
#define CLS 4
#define KParts 16
#define CAP 4096
#define NB3 ((N + 255) / 256)       // 782 blocks for the dots part
#define NWAVES ((N + 63) / 64)      // 3125 full waves own columns

typedef float v2f __attribute__((ext_vector_type(2)));

// ws float offsets
static const size_t OFF_U     = 0;                           // C*N uints (ordering keys)
static const size_t OFF_TESQ  = (size_t)C * N;               // N floats
static const size_t OFF_GPART = OFF_TESQ + N;                // KParts*2500
static const size_t OFF_WPART = OFF_GPART + KParts * 2500;   // KParts*200
static const size_t OFF_RANGE = OFF_WPART + KParts * 200;    // NWAVES*2 uints (pad 3200*2)
static const size_t OFF_SUMS  = OFF_RANGE + 6400;            // C floats
static const size_t OFF_CNT   = OFF_SUMS + C;                // 1 uint
static const size_t OFF_GR    = OFF_CNT + 1;                 // 2 uints: global ulo/uhi
static const size_t OFF_W8    = ((OFF_GR + 2 + 3) / 4) * 4;  // D*8 floats, 16B-aligned

__device__ __forceinline__ unsigned mapf(float v) {
    unsigned u = __float_as_uint(v);
    return (u & 0x80000000u) ? ~u : (u | 0x80000000u);
}
__device__ __forceinline__ float unmapf(unsigned u) {
    unsigned b = (u & 0x80000000u) ? (u ^ 0x80000000u) : ~u;
    return __uint_as_float(b);
}
// ordering key: tesq - 2*dot (monotone with dist2; csq constant per concept)
__device__ __forceinline__ unsigned keyu(float dot, float tesq) {
    return mapf(fmaf(-2.0f, dot, tesq));
}

// ---------------- KA: keys+tesq+per-wave range (782 blocks) fused with partial gram/wc (16) ----
__global__ __launch_bounds__(256) void kA_dots_gram(
    const float* __restrict__ concept, const float* __restrict__ te,
    const float* __restrict__ hxw, float* __restrict__ ws)
{
    int t = threadIdx.x;
    if (blockIdx.x < NB3) {
        int n = blockIdx.x * 256 + t;
        if (n >= N) return;   // whole-wave exits only; no barriers in this branch

        v2f acc[25];
        #pragma unroll
        for (int q = 0; q < 25; ++q) acc[q] = (v2f)(0.0f);
        float tesq = 0.f;

        const float* tp = te + n;
        for (int d0 = 0; d0 < D; d0 += 16) {
            float x[16];
            #pragma unroll
            for (int u = 0; u < 16; ++u)
                x[u] = tp[(size_t)(d0 + u) * N];
            #pragma unroll
            for (int u = 0; u < 16; ++u) {
                tesq = fmaf(x[u], x[u], tesq);
                const v2f* crow = (const v2f*)(concept + (d0 + u) * 50); // wave-uniform
                v2f xv; xv[0] = x[u]; xv[1] = x[u];
                #pragma unroll
                for (int q = 0; q < 25; ++q)
                    acc[q] = __builtin_elementwise_fma(xv, crow[q], acc[q]);
            }
        }

        unsigned* uws = (unsigned*)ws;
        unsigned umin = 0xFFFFFFFFu, umax = 0u;
        #pragma unroll
        for (int q = 0; q < 25; ++q) {
            unsigned u0 = keyu(acc[q][0], tesq);
            unsigned u1 = keyu(acc[q][1], tesq);
            uws[(size_t)(2 * q) * N + n]     = u0;
            uws[(size_t)(2 * q + 1) * N + n] = u1;
            umin = min(umin, min(u0, u1));
            umax = max(umax, max(u0, u1));
        }
        ws[OFF_TESQ + n] = tesq;

        // wave-reduce range, one slot per wave (no atomics, no init needed)
        #pragma unroll
        for (int off = 32; off > 0; off >>= 1) {
            umin = min(umin, (unsigned)__shfl_down((int)umin, off, 64));
            umax = max(umax, (unsigned)__shfl_down((int)umax, off, 64));
        }
        if ((t & 63) == 0) {
            int w = n >> 6;
            ((unsigned*)(ws + OFF_RANGE))[2 * w]     = umin;
            ((unsigned*)(ws + OFF_RANGE))[2 * w + 1] = umax;
        }
    } else {
        // ---- partial gram + partial wc over a 64-row d-slab ----
        __shared__ __align__(16) float ct[64 * 50];
        __shared__ float hs[4 * 64];
        int bid = blockIdx.x - NB3;
        int d0 = bid * 64;

        for (int i = t; i < 64 * 50; i += 256) ct[i] = concept[d0 * 50 + i];
        {
            int j = t >> 6, dd = t & 63;
            hs[t] = hxw[j * D + d0 + dd];
        }
        __syncthreads();

        float* gp = ws + OFF_GPART + (size_t)bid * 2500;
        for (int p = t; p < 2500; p += 256) {
            int i = p / 50, j = p - i * 50;
            float acc = 0.f;
            #pragma unroll 8
            for (int dd = 0; dd < 64; ++dd)
                acc = fmaf(ct[dd * 50 + i], ct[dd * 50 + j], acc);
            gp[p] = acc;
        }
        float* wp = ws + OFF_WPART + (size_t)bid * 200;
        if (t < 200) {
            int j = t / 50, c = t - j * 50;
            float acc = 0.f;
            #pragma unroll 8
            for (int dd = 0; dd < 64; ++dd)
                acc = fmaf(hs[j * 64 + dd], ct[dd * 50 + c], acc);
            wp[t] = acc;
        }
    }
}

// ---------------- K1b: reduce partials+range, metrics, solve [G|wc^T], W8 ----------
__global__ __launch_bounds__(256) void k1b_solve(
    const float* __restrict__ concept, const float* __restrict__ hxw,
    float* __restrict__ ws, float* __restrict__ out)
{
    __shared__ float gsh[2500];
    __shared__ float A[50 * 56];     // [G | wc^T | pad]
    __shared__ float colp[C];
    __shared__ float part[3][4];
    __shared__ unsigned ured[2][4];
    int t = threadIdx.x;
    int lane = t & 63, wid = t >> 6;

    if (t == 0) ((unsigned*)(ws + OFF_CNT))[0] = 0u;   // k4 completion counter

    // global key range from wave slots
    {
        const unsigned* rg = (const unsigned*)(ws + OFF_RANGE);
        unsigned mn = 0xFFFFFFFFu, mx = 0u;
        for (int i = t; i < NWAVES; i += 256) {
            mn = min(mn, rg[2 * i]);
            mx = max(mx, rg[2 * i + 1]);
        }
        #pragma unroll
        for (int off = 32; off > 0; off >>= 1) {
            mn = min(mn, (unsigned)__shfl_down((int)mn, off, 64));
            mx = max(mx, (unsigned)__shfl_down((int)mx, off, 64));
        }
        if (lane == 0) { ured[0][wid] = mn; ured[1][wid] = mx; }
    }

    float s_all = 0.f, s_tr = 0.f, s_abs = 0.f;
    for (int p = t; p < 2500; p += 256) {
        float g = 0.f;
        #pragma unroll
        for (int b = 0; b < KParts; ++b)
            g += ws[OFF_GPART + (size_t)b * 2500 + p];
        gsh[p] = g;
        int i = p / 50, j = p - i * 50;
        float e = (i == j) ? 1.0f : 0.0f;
        s_all += g;
        if (i == j) s_tr += g;
        s_abs += fabsf(g - e);
    }
    #pragma unroll
    for (int off = 32; off > 0; off >>= 1) {
        s_all += __shfl_down(s_all, off, 64);
        s_tr  += __shfl_down(s_tr,  off, 64);
        s_abs += __shfl_down(s_abs, off, 64);
    }
    if (lane == 0) { part[0][wid] = s_all; part[1][wid] = s_tr; part[2][wid] = s_abs; }
    __syncthreads();
    if (t == 0) {
        float a  = part[0][0] + part[0][1] + part[0][2] + part[0][3];
        float tr = part[1][0] + part[1][1] + part[1][2] + part[1][3];
        float ab = part[2][0] + part[2][1] + part[2][2] + part[2][3];
        out[32769] = (a - tr) / 2500.0f;   // L_sparse_2
        out[32770] = tr / 2500.0f;         // norm_metrics
        out[32771] = ab / 2500.0f;         // similarity_penalty
        unsigned mn = min(min(ured[0][0], ured[0][1]), min(ured[0][2], ured[0][3]));
        unsigned mx = max(max(ured[1][0], ured[1][1]), max(ured[1][2], ured[1][3]));
        ((unsigned*)(ws + OFF_GR))[0] = mn;
        ((unsigned*)(ws + OFF_GR))[1] = mx;
    }

    for (int p = t; p < 50 * 56; p += 256) {
        int r = p / 56, col = p - r * 56;
        float v = 0.f;
        if (col < 50) v = gsh[r * 50 + col];
        else if (col < 54) {
            float w = 0.f;
            #pragma unroll
            for (int b = 0; b < KParts; ++b)
                w += ws[OFF_WPART + (size_t)b * 200 + (col - 50) * 50 + r];
            v = w;
        }
        A[p] = v;
    }
    __syncthreads();

    // pivotless Gauss-Jordan (G is SPD -> stable without pivoting)
    for (int pc = 0; pc < C; ++pc) {
        if (t < C) colp[t] = A[t * 56 + pc];
        __syncthreads();
        float pinv = 1.0f / colp[pc];
        if (t < 56) A[pc * 56 + t] *= pinv;
        __syncthreads();
        for (int p = t; p < 50 * 56; p += 256) {
            int r = p / 56, col = p - r * 56;
            if (r != pc) A[p] = fmaf(-colp[r], A[pc * 56 + col], A[p]);
        }
        __syncthreads();
    }

    // W8[d][0..3] = hxw[j][d]; W8[d][4..7] = sum_c concept[d][c] * A[c][50+j]
    for (int d = t; d < D; d += 256) {
        float wy0 = 0.f, wy1 = 0.f, wy2 = 0.f, wy3 = 0.f;
        for (int c = 0; c < C; ++c) {
            float cv = concept[d * 50 + c];
            wy0 = fmaf(cv, A[c * 56 + 50], wy0);
            wy1 = fmaf(cv, A[c * 56 + 51], wy1);
            wy2 = fmaf(cv, A[c * 56 + 52], wy2);
            wy3 = fmaf(cv, A[c * 56 + 53], wy3);
        }
        float4 lo, hi;
        lo.x = hxw[0 * D + d]; lo.y = hxw[1 * D + d];
        lo.z = hxw[2 * D + d]; lo.w = hxw[3 * D + d];
        hi.x = wy0; hi.y = wy1; hi.z = wy2; hi.w = wy3;
        *(float4*)(ws + OFF_W8 + (size_t)d * 8)     = lo;
        *(float4*)(ws + OFF_W8 + (size_t)d * 8 + 4) = hi;
    }
}

// ---------------- Kpred: [orig_pred | y_pred] = X @ W8 + bias -----------------
__global__ __launch_bounds__(256) void kpred(
    const float* __restrict__ X, const float* __restrict__ hxb,
    const float* __restrict__ ws, float* __restrict__ out)
{
    int t = threadIdx.x;
    int lane = t & 63, w = t >> 6;
    int r = blockIdx.x * 4 + w;
    const float* xr = X + (size_t)r * D;
    const float* w8 = ws + OFF_W8;

    float acc[8];
    #pragma unroll
    for (int j = 0; j < 8; ++j) acc[j] = 0.f;
    #pragma unroll
    for (int i = 0; i < 16; ++i) {
        int d = i * 64 + lane;
        float x = xr[d];
        float4 lo = *(const float4*)(w8 + (size_t)d * 8);
        float4 hi = *(const float4*)(w8 + (size_t)d * 8 + 4);
        acc[0] = fmaf(x, lo.x, acc[0]);
        acc[1] = fmaf(x, lo.y, acc[1]);
        acc[2] = fmaf(x, lo.z, acc[2]);
        acc[3] = fmaf(x, lo.w, acc[3]);
        acc[4] = fmaf(x, hi.x, acc[4]);
        acc[5] = fmaf(x, hi.y, acc[5]);
        acc[6] = fmaf(x, hi.z, acc[6]);
        acc[7] = fmaf(x, hi.w, acc[7]);
    }
    #pragma unroll
    for (int j = 0; j < 8; ++j) {
        float v = acc[j];
        #pragma unroll
        for (int off = 32; off > 0; off >>= 1) v += __shfl_down(v, off, 64);
        if (lane == 0) {
            float b = hxb[j & 3];
            if (j < 4) out[(size_t)r * CLS + j] = v + b;
            else       out[16384 + (size_t)r * CLS + (j - 4)] = v + b;
        }
    }
}

// ---------------- K4: top-k from u keys (1 histogram + 1 final pass) + fused L_sparse_1 ------
__global__ __launch_bounds__(1024) void k4_select(
    const float* __restrict__ ws, float* __restrict__ wsw,
    float* __restrict__ out, const int* __restrict__ topk)
{
    int c = blockIdx.x, t = threadIdx.x;
    int lane = t & 63, wid = t >> 6;
    const unsigned* uarr = (const unsigned*)ws + (size_t)c * N;
    const float* tesq = ws + OFF_TESQ;

    __shared__ unsigned hist[4096];
    __shared__ unsigned wsum[16], woff[16];
    __shared__ unsigned sh_bin; __shared__ int sh_rem;
    __shared__ int cnt;
    __shared__ unsigned cand_u[CAP];
    __shared__ int      cand_i[CAP];
    __shared__ float fred[16];

    unsigned ulo = ((const unsigned*)(ws + OFF_GR))[0];
    unsigned uhi = ((const unsigned*)(ws + OFF_GR))[1];
    int rem = *topk;
    unsigned long long width = (unsigned long long)(uhi - ulo) + 1ull;

    // ---- pass 1: histogram over 4096 linear bins of the global range ----
    for (int i = t; i < 4096; i += 1024) hist[i] = 0u;
    __syncthreads();
    for (int n = t; n < N; n += 1024) {
        unsigned u = uarr[n];
        unsigned bin = (unsigned)(((unsigned long long)(u - ulo) * 4096ull) / width);
        atomicAdd(&hist[bin], 1u);
    }
    __syncthreads();
    {
        unsigned b0 = (unsigned)t * 4u;
        unsigned h0 = hist[b0], h1 = hist[b0 + 1], h2 = hist[b0 + 2], h3 = hist[b0 + 3];
        unsigned s4 = h0 + h1 + h2 + h3;
        unsigned x = s4;
        #pragma unroll
        for (int off = 1; off < 64; off <<= 1) {
            unsigned y = (unsigned)__shfl_up((int)x, off, 64);
            if (lane >= off) x += y;
        }
        if (lane == 63) wsum[wid] = x;
        __syncthreads();
        if (t == 0) {
            unsigned run = 0;
            for (int w = 0; w < 16; ++w) { woff[w] = run; run += wsum[w]; }
        }
        __syncthreads();
        unsigned cumBefore = woff[wid] + x - s4;
        unsigned remu = (unsigned)rem;
        if (cumBefore < remu && remu <= cumBefore + s4) {
            unsigned cum = cumBefore, bin = b0, r2 = 1;
            unsigned hh[4] = {h0, h1, h2, h3};
            #pragma unroll
            for (int j = 0; j < 4; ++j) {
                if (cum + hh[j] >= remu) { bin = b0 + j; r2 = remu - cum; break; }
                cum += hh[j];
            }
            sh_bin = bin; sh_rem = (int)r2;
        }
        __syncthreads();
        unsigned b = sh_bin;
        rem = sh_rem;
        ulo = ulo + (unsigned)(((unsigned long long)b * width + 4095ull) / 4096ull);
        uhi = ((const unsigned*)(ws + OFF_GR))[0]
              + (unsigned)((((unsigned long long)(b + 1) * width + 4095ull) / 4096ull) - 1ull);
        __syncthreads();
    }

    // ---- final: sum recovered dots below cutoff bin; collect cutoff-bin candidates ----
    if (t == 0) cnt = 0;
    __syncthreads();
    float lsum = 0.f;
    for (int n = t; n < N; n += 1024) {
        unsigned u = uarr[n];
        if (u < ulo) {
            // dot = (tesq - key)/2, exact to half-ulp of key
            lsum += 0.5f * (tesq[n] - unmapf(u));
        } else if (u <= uhi) {
            int s = atomicAdd(&cnt, 1);
            if (s < CAP) { cand_u[s] = u; cand_i[s] = n; }
        }
    }
    __syncthreads();
    int cc = cnt < CAP ? cnt : CAP;
    for (int ci = t; ci < cc; ci += 1024) {
        unsigned ui = cand_u[ci]; int ii = cand_i[ci];
        int rank = 0;
        for (int j = 0; j < cc; ++j) {
            unsigned uj = cand_u[j];
            rank += (uj < ui || (uj == ui && cand_i[j] < ii)) ? 1 : 0;
        }
        if (rank < rem) lsum += 0.5f * (tesq[ii] - unmapf(ui));
    }
    #pragma unroll
    for (int off = 32; off > 0; off >>= 1) lsum += __shfl_down(lsum, off, 64);
    if (lane == 0) fred[wid] = lsum;
    __syncthreads();
    if (t == 0) {
        float tot = 0.f;
        for (int w = 0; w < 16; ++w) tot += fred[w];
        wsw[OFF_SUMS + c] = tot;
        __threadfence();
        unsigned done = atomicAdd((unsigned*)(wsw + OFF_CNT), 1u);
        if (done == C - 1) {
            float s = 0.f;
            for (int i = 0; i < C; ++i) s += atomicAdd(&wsw[OFF_SUMS + i], 0.0f);
            out[32768] = s / (float)((*topk) * C);
        }
    }
}

extern "C" void kernel_launch(void* const* d_in, const int* in_sizes, int n_in,
                              void* d_out, int out_size, void* d_ws, size_t ws_size,
                              hipStream_t stream) {
    (void)in_sizes; (void)n_in; (void)out_size; (void)ws_size;
    const float* concept = (const float*)d_in[0];
    const float* te      = (const float*)d_in[1];
    const float* X       = (const float*)d_in[2];
    const float* hxw     = (const float*)d_in[3];
    const float* hxb     = (const float*)d_in[4];
    const int*   topk    = (const int*)d_in[5];
    float* out = (float*)d_out;
    float* ws  = (float*)d_ws;

    kA_dots_gram<<<dim3(NB3 + KParts), dim3(256), 0, stream>>>(concept, te, hxw, ws);
    k1b_solve<<<dim3(1), dim3(256), 0, stream>>>(concept, hxw, ws, out);
    kpred<<<dim3(B / 4), dim3(256), 0, stream>>>(X, hxb, ws, out);
    k4_select<<<dim3(C), dim3(1024), 0, stream>>>(ws, ws, out, topk);
}